// Round 9
// baseline (143.148 us; speedup 1.0000x reference)
//
#include <hip/hip_runtime.h>
#include <stdint.h>

// q,k,v: [B=8, d=768, N=6144] fp32; head_dim=32, kernel_size=3
// h=24 heads, g=2048 windows; window elem j of window gg at n = j*2048 + gg
// out flat: [b][gg][hh][kq][dd] contiguous [8, 2048, 24, 3, 32]
//
// Round 9: DRAM-page-locality design (rounds 4-8 showed BW pinned at
// ~2.3-2.9 TB/s across 27%..77% occupancy -> not concurrency-bound; the
// 64B-island access pattern is activate-rate-bound at DRAM).
//  - Block (256 thr) owns (b, hh, 256 windows). All global reads are staged
//    through LDS with each wave instruction covering EXACTLY one contiguous
//    1KB (row,j)-segment (64 lanes x float4); a block drains 24-48KB per
//    burst -> full DRAM pages consumed per activate.
//  - Score phase: 4 chunks of 8 dd-rows (q 24KB + k 24KB in LDS).
//    Compute reads LDS at lane-stride-1 (2-way bank alias = free).
//  - V phase: 2 chunks of 16 dd-rows (48KB, reusing the same buffer);
//    each thread then stores one FULL 64B line per kq per chunk -> amp-free.
//  - Traffic unchanged (every input element read exactly once).
//  - 48KB LDS -> 3 blocks/CU (12 waves/CU); occupancy proven non-binding.
constexpr int CB = 8;
constexpr int CD = 768;
constexpr int CN = 6144;
constexpr int HD = 32;
constexpr int KS = 3;
constexpr int CH = CD / HD;     // 24
constexpr int CG = CN / KS;     // 2048
constexpr int W  = 256;         // windows per block
constexpr int NGB = CG / W;     // 8 gg-chunks per (b,hh)
constexpr int DCS = 8;          // dd rows per score chunk
constexpr int DCV = 16;         // dd rows per v chunk
constexpr int ROWF  = KS * W;   // 768 staged floats per row (3 x 1KB segs)
constexpr int ROWF4 = ROWF / 4; // 192 float4 per row
constexpr int OSTR  = CH * KS * HD;  // 2304 floats per (b,gg) out block

__global__ __launch_bounds__(256) void dilate_attn_kernel(
    const float* __restrict__ q, const float* __restrict__ k,
    const float* __restrict__ v, float* __restrict__ out) {
  __shared__ float smem[2 * DCS * ROWF];  // 12288 floats = 48 KB
  const int t   = threadIdx.x;
  const int bid = blockIdx.x;
  const int gc  = bid & (NGB - 1);        // gg-chunk fastest: adjacent blocks
  const int bh  = bid >> 3;               // read adjacent 1KB segments
  const int hh  = bh % CH;
  const int b   = bh / CH;
  const int g0  = gc * W;

  // float offset of (row dd=hh*32, j=0, col g0); row dd at +dd*CN, seg j at +j*CG
  const uint32_t rowbase = (uint32_t)(b * CD + hh * HD) * (uint32_t)CN + (uint32_t)g0;

  float s[3][3] = {{0.f, 0.f, 0.f}, {0.f, 0.f, 0.f}, {0.f, 0.f, 0.f}};

  // ================= score phase: 4 chunks of 8 rows =================
  for (int cc = 0; cc < HD / DCS; ++cc) {
    const uint32_t cbase = rowbase + (uint32_t)(cc * DCS) * (uint32_t)CN;
    // stage q-chunk -> smem[0..6144), k-chunk -> smem[6144..12288)
    // flat f4 index == LDS f4 index; each wave-instruction = one 1KB segment
    #pragma unroll
    for (int i = 0; i < 6; ++i) {
      const int f4  = i * 256 + t;
      const int r   = f4 / ROWF4;
      const int rem = f4 % ROWF4;
      const int j   = rem / (W / 4);
      const int c4  = rem % (W / 4);
      const uint32_t go = cbase + (uint32_t)r * CN + (uint32_t)j * CG + (uint32_t)(c4 * 4);
      reinterpret_cast<float4*>(smem)[f4] =
          *reinterpret_cast<const float4*>(q + go);
      reinterpret_cast<float4*>(smem)[6 * 256 + f4] =
          *reinterpret_cast<const float4*>(k + go);
    }
    __syncthreads();
    // accumulate scores for window g0+t from LDS (lane-stride-1 reads)
    #pragma unroll
    for (int r = 0; r < DCS; ++r) {
      const float* qr = smem + r * ROWF;
      const float* kr = smem + DCS * ROWF + r * ROWF;
      const float q0 = qr[t], q1 = qr[W + t], q2 = qr[2 * W + t];
      const float k0 = kr[t], k1 = kr[W + t], k2 = kr[2 * W + t];
      s[0][0] = fmaf(q0, k0, s[0][0]);
      s[0][1] = fmaf(q0, k1, s[0][1]);
      s[0][2] = fmaf(q0, k2, s[0][2]);
      s[1][0] = fmaf(q1, k0, s[1][0]);
      s[1][1] = fmaf(q1, k1, s[1][1]);
      s[1][2] = fmaf(q1, k2, s[1][2]);
      s[2][0] = fmaf(q2, k0, s[2][0]);
      s[2][1] = fmaf(q2, k1, s[2][1]);
      s[2][2] = fmaf(q2, k2, s[2][2]);
    }
    __syncthreads();  // protect smem before next stage overwrites
  }

  // ================= softmax over kj, in place =================
  const float scale = 0.17677669529663687f;  // 32^-0.5
  #pragma unroll
  for (int a = 0; a < 3; ++a) {
    const float x0 = s[a][0] * scale, x1 = s[a][1] * scale, x2 = s[a][2] * scale;
    const float m  = fmaxf(fmaxf(x0, x1), x2);
    const float e0 = __expf(x0 - m), e1 = __expf(x1 - m), e2 = __expf(x2 - m);
    const float r  = 1.f / (e0 + e1 + e2);
    s[a][0] = e0 * r; s[a][1] = e1 * r; s[a][2] = e2 * r;
  }

  // ================= v phase: 2 chunks of 16 rows =================
  // out float offset for window g0+t: (b*CG + g0 + t)*2304 + hh*96
  const uint32_t obase = (uint32_t)(b * CG + g0 + t) * (uint32_t)OSTR
                       + (uint32_t)(hh * KS * HD);
  for (int cc = 0; cc < HD / DCV; ++cc) {
    const uint32_t cbase = rowbase + (uint32_t)(cc * DCV) * (uint32_t)CN;
    #pragma unroll
    for (int i = 0; i < 12; ++i) {
      const int f4  = i * 256 + t;
      const int r   = f4 / ROWF4;
      const int rem = f4 % ROWF4;
      const int j   = rem / (W / 4);
      const int c4  = rem % (W / 4);
      const uint32_t go = cbase + (uint32_t)r * CN + (uint32_t)j * CG + (uint32_t)(c4 * 4);
      reinterpret_cast<float4*>(smem)[f4] =
          *reinterpret_cast<const float4*>(v + go);
    }
    __syncthreads();
    // PV for window g0+t over this chunk's 16 dd
    float o[3][DCV];
    #pragma unroll
    for (int r = 0; r < DCV; ++r) {
      const float* vr = smem + r * ROWF;
      const float v0 = vr[t], v1 = vr[W + t], v2 = vr[2 * W + t];
      #pragma unroll
      for (int a = 0; a < 3; ++a)
        o[a][r] = fmaf(s[a][0], v0, fmaf(s[a][1], v1, s[a][2] * v2));
    }
    // store: per kq one full aligned 64B line (16 floats, back-to-back)
    #pragma unroll
    for (int a = 0; a < 3; ++a) {
      float* op = out + obase + a * HD + cc * DCV;
      #pragma unroll
      for (int c = 0; c < 4; ++c)
        reinterpret_cast<float4*>(op)[c] =
            make_float4(o[a][c * 4], o[a][c * 4 + 1], o[a][c * 4 + 2], o[a][c * 4 + 3]);
    }
    __syncthreads();  // protect smem before next stage overwrites
  }
}

extern "C" void kernel_launch(void* const* d_in, const int* in_sizes, int n_in,
                              void* d_out, int out_size, void* d_ws, size_t ws_size,
                              hipStream_t stream) {
  const float* q = (const float*)d_in[0];
  const float* k = (const float*)d_in[1];
  const float* v = (const float*)d_in[2];
  float* out = (float*)d_out;

  const int blocks = CB * CH * NGB;   // 8*24*8 = 1536 blocks, 256 thr each
  dilate_attn_kernel<<<blocks, 256, 0, stream>>>(q, k, v, out);
}